// Round 12
// baseline (2841.779 us; speedup 1.0000x reference)
//
#include <hip/hip_runtime.h>
#include <hip/hip_bf16.h>
#include <math.h>

// Problem constants
#define T 256
#define B 64
#define FEAT 256
#define HID 1024
#define NCLS 257
#define NCH 4              // independent batch chains (16 batches each)
#define NBLK 256
#define NTHR 512
#define HSLOT 16384        // shorts per (t,chain) h slot: 128 rows x 16 b x 8
#define XSLOT 4096         // shorts per (t,chain) x slot: 32 rows x 16 b x 8

typedef __attribute__((ext_vector_type(8))) short short8v;   // 8 x bf16
typedef __attribute__((ext_vector_type(4))) float floatx4;   // MFMA acc

// Hamilton block component/sign tables
__device__ __constant__ int   d_comp[4][4] = {{0,1,2,3},{1,0,3,2},{2,3,0,1},{3,2,1,0}};
__device__ __constant__ float d_sign[4][4] = {{ 1.f, 1.f, 1.f, 1.f},
                                              {-1.f, 1.f,-1.f, 1.f},
                                              {-1.f, 1.f, 1.f,-1.f},
                                              {-1.f,-1.f, 1.f, 1.f}};

__device__ __forceinline__ ushort f2bf(float f) {
    union { float f; unsigned u; } v; v.f = f;
    unsigned r = v.u + 0x7FFF + ((v.u >> 16) & 1);   // RNE
    return (ushort)(r >> 16);
}

__device__ __forceinline__ float sigm(float v) { return 1.f / (1.f + __expf(-v)); }
__device__ __forceinline__ float tanh_fast(float v) { return 1.f - 2.f / (1.f + __expf(2.f * v)); }

// x (fp32 [T][B][FEAT]) -> per-(t,chain) panels xp[t*4+c][FEAT/8][16][8] bf16
__global__ __launch_bounds__(256) void conv_xpanel(const float* __restrict__ x,
                                                   ushort* __restrict__ xp) {
    int i = blockIdx.x * 256 + threadIdx.x;   // over T*B*FEAT/4
    int k4 = i & 63, b = (i >> 6) & 63, t = i >> 12;
    int k = k4 * 4;
    int c = b >> 4, b16 = b & 15;
    float4 v = ((const float4*)x)[i];
    ushort4 o;
    o.x = f2bf(v.x); o.y = f2bf(v.y); o.z = f2bf(v.z); o.w = f2bf(v.w);
    *(ushort4*)(xp + (size_t)(t * 4 + c) * XSLOT + (k >> 3) * 128 + b16 * 8 + (k & 7)) = o;
}

// Frag-ordered bf16 weights (A = W^T), per (cg, mt):
// e = (((cg*4 + mt)*40 + ks)*64 + lane)*8 + j
__global__ __launch_bounds__(256) void prep_wcf(const float* __restrict__ Wh,
                                                const float* __restrict__ Wx,
                                                ushort* __restrict__ wcf) {
    int e = blockIdx.x * 256 + threadIdx.x;   // < 64*4*40*512 = 5,242,880
    int j    = e & 7;
    int lane = (e >> 3) & 63;
    int r    = e >> 9;
    int ks   = r % 40;
    int s    = r / 40;
    int mt   = s & 3;
    int cg   = s >> 2;
    int c  = mt * 16 + (lane & 15);
    int hl = c >> 2, g = c & 3;
    int n  = cg * 16 + hl;
    int qq = n >> 8, bc = n & 255;
    int k  = ks * 32 + ((lane >> 4) << 3) + j;
    float v;
    if (k < HID) {
        int p = k >> 8, a = k & 255;
        v = d_sign[p][qq] * Wh[((g * 4 + d_comp[p][qq]) * 256 + a) * 256 + bc];
    } else {
        int kk = k - HID;
        int p = kk >> 6, a = kk & 63;
        v = d_sign[p][qq] * Wx[((g * 4 + d_comp[p][qq]) * 64 + a) * 256 + bc];
    }
    wcf[e] = f2bf(v);
}

// Wo -> frag-ordered bf16, cols padded to 320
__global__ __launch_bounds__(256) void prep_wof(const float* __restrict__ Wo,
                                                ushort* __restrict__ wof) {
    int e = blockIdx.x * 256 + threadIdx.x;   // < 20*32*512 = 327,680
    int j    = e & 7;
    int lane = (e >> 3) & 63;
    int ks   = (e >> 9) & 31;
    int tile = e >> 14;
    int n = tile * 16 + (lane & 15);
    int k = ks * 32 + ((lane >> 4) << 3) + j;
    wof[e] = (n < NCLS) ? f2bf(Wo[k * NCLS + n]) : (ushort)0;
}

// zero h slots 0..3 (t=0 input) and the 1024-byte flag region
__global__ __launch_bounds__(256) void init_hf(ushort* __restrict__ hpan,
                                               unsigned char* __restrict__ flg) {
    int i = blockIdx.x * 256 + threadIdx.x;   // 64 blocks -> 16384 threads
    ((ushort4*)hpan)[i] = make_ushort4(0, 0, 0, 0);   // 65536 shorts = slots 0..3
    if (blockIdx.x == 0 && threadIdx.x < 64)
        ((uint4*)flg)[threadIdx.x] = make_uint4(0, 0, 0, 0);
}

#define LOADX4SC(dst, addr) \
    asm volatile("global_load_dwordx4 %0, %1, off sc0 sc1" : "=v"(dst) : "v"(addr))
#define LOADX4(dst, addr) \
    asm volatile("global_load_dwordx4 %0, %1, off" : "=v"(dst) : "v"(addr))

// Persistent kernel: 4 independent chains. Block blk -> (chain = blk&3,
// cg = blk>>2): 16 hidden cols (64 gate cols) x 16 batches. 8 waves:
// mt = w&3, kh = w>>2; wave kh: h-ksteps kh*16..+15, x-ksteps kh*4..+3.
// Flags: 1 byte per (chain, gate-wave, cg) -> 4 lines/chain, polled with a
// single dwordx4 sc-load per lane. Per-wave flagging after own vmcnt(0);
// parity-buffered LDS -> exactly one __syncthreads per step.
__global__ __launch_bounds__(512, 2) void qlstm_persist(
    const ushort* __restrict__ xp,    // x panels [T*4][XSLOT]
    const ushort* __restrict__ wcf,   // frag-ordered weights
    const float*  __restrict__ bx,    // [4][1024]
    ushort*       __restrict__ hpan,  // h panels [(T+1)*4][HSLOT]
    unsigned char* __restrict__ flg)  // [4][4][64] bytes: chain, gatewave, cg
{
    __shared__ float pre[2][2][16][72];   // [parity][kh][batch][gatecol pad]

    const int tid  = threadIdx.x;
    const int blk  = blockIdx.x;
    const int ch   = blk & 3;
    const int cg   = blk >> 2;
    const int w    = tid >> 6;
    const int lane = tid & 63;
    const int mt   = w & 3;
    const int kh   = w >> 2;
    const int lofs = (lane >> 4) * 128 + (lane & 15) * 8;   // shorts

    // ---- one-time: A-frags via asm loads (stay register-resident) ----
    const ushort* wbase = wcf + (size_t)(cg * 4 + mt) * 40 * 512 + lane * 8;
    short8v A[16], Ax[4];
    #pragma unroll
    for (int i = 0; i < 16; ++i) LOADX4(A[i], wbase + (kh * 16 + i) * 512);
    #pragma unroll
    for (int u = 0; u < 4; ++u)  LOADX4(Ax[u], wbase + (32 + kh * 4 + u) * 512);
    asm volatile("s_waitcnt vmcnt(0)" ::: "memory");
    __builtin_amdgcn_sched_barrier(0);

    // ---- gate identity (tid<256): (gb = batch-local, hl = hidden-local) ----
    const int gb = tid >> 4;
    const int hl = tid & 15;
    const int gn = cg * 16 + hl;
    float bxf = 0.f, bxi = 0.f, bxo = 0.f, bxa = 0.f;
    if (tid < 256) {
        bxf = bx[gn]; bxi = bx[HID + gn];
        bxo = bx[2 * HID + gn]; bxa = bx[3 * HID + gn];
    }
    float c_reg = 0.f;
    const int st_off = (cg * 2 + (hl >> 3)) * 128 + gb * 8 + (hl & 7);
    const uint* pollp = (const uint*)(flg + ch * 256) + (lane & 15) * 4;
    unsigned char* myflag = flg + ch * 256 + w * 64 + cg;   // gate waves only

    for (int t = 0; t < T; ++t) {
        const ushort* hs = hpan + (size_t)(t * NCH + ch) * HSLOT;
        const ushort* xs = xp   + (size_t)(t * NCH + ch) * XSLOT;
        const int par = t & 1;

        // 1. x loads + x MFMAs (independent of h_t; overlaps the poll window)
        short8v xv[4];
        #pragma unroll
        for (int u = 0; u < 4; ++u) LOADX4(xv[u], xs + (kh * 4 + u) * 512 + lofs);
        asm volatile("s_waitcnt vmcnt(0)" ::: "memory");
        __builtin_amdgcn_sched_barrier(0);
        floatx4 a0 = {0.f,0.f,0.f,0.f}, a1 = {0.f,0.f,0.f,0.f};
        a0 = __builtin_amdgcn_mfma_f32_16x16x32_bf16(Ax[0], xv[0], a0, 0, 0, 0);
        a1 = __builtin_amdgcn_mfma_f32_16x16x32_bf16(Ax[1], xv[1], a1, 0, 0, 0);
        a0 = __builtin_amdgcn_mfma_f32_16x16x32_bf16(Ax[2], xv[2], a0, 0, 0, 0);
        a1 = __builtin_amdgcn_mfma_f32_16x16x32_bf16(Ax[3], xv[3], a1, 0, 0, 0);

        // 2. poll: all waves; one dwordx4 sc-load per lane covers the chain's
        //    256 flag bytes; byte value (t-1)&127 + 1 replicated as dword
        if (t > 0) {
            const uint rep = (uint)(((t - 1) & 127) + 1) * 0x01010101u;
            for (;;) {
                uint4 F;
                LOADX4SC(F, pollp);
                asm volatile("s_waitcnt vmcnt(0)" ::: "memory");
                if (__all((F.x == rep) && (F.y == rep) &&
                          (F.z == rep) && (F.w == rep))) break;
                __builtin_amdgcn_s_sleep(1);
            }
        }

        // 3. h loads (sc0sc1: one-hop MALL, no L2 staleness)
        short8v Bh[16];
        #pragma unroll
        for (int i = 0; i < 16; ++i)
            LOADX4SC(Bh[i], hs + (kh * 16 + i) * 512 + lofs);
        asm volatile("s_waitcnt vmcnt(0)" ::: "memory");
        __builtin_amdgcn_sched_barrier(0);

        // 4. h MFMAs
        #pragma unroll
        for (int i = 0; i < 16; i += 2) {
            a0 = __builtin_amdgcn_mfma_f32_16x16x32_bf16(A[i],     Bh[i],     a0, 0, 0, 0);
            a1 = __builtin_amdgcn_mfma_f32_16x16x32_bf16(A[i + 1], Bh[i + 1], a1, 0, 0, 0);
        }
        floatx4 acc = a0 + a1;

        // 5. stage to LDS (parity-buffered), single barrier per step
        {
            float4 v = make_float4(acc[0], acc[1], acc[2], acc[3]);
            *(float4*)&pre[par][kh][lane & 15][mt * 16 + (lane >> 4) * 4] = v;
        }
        __syncthreads();

        // 6. gates (waves 0-3): compute h, store, ack own stores, flag own byte
        if (tid < 256) {
            float4 p0 = *(const float4*)&pre[par][0][gb][hl * 4];
            float4 p1 = *(const float4*)&pre[par][1][gb][hl * 4];
            float f  = sigm(p0.x + p1.x + bxf);
            float i_ = sigm(p0.y + p1.y + bxi);
            float o  = sigm(p0.z + p1.z + bxo);
            float a  = p0.w + p1.w + bxa;
            c_reg = i_ * tanh_fast(a) + f * c_reg;
            float h = o * tanh_fast(c_reg);
            uint hvu = f2bf(h);
            ushort* hp = hpan + (size_t)((t + 1) * NCH + ch) * HSLOT + st_off;
            asm volatile("global_store_short %0, %1, off sc0 sc1"
                         :: "v"(hp), "v"(hvu) : "memory");
            asm volatile("s_waitcnt vmcnt(0)" ::: "memory");
            if (lane == 0) {
                uint fv = (uint)((t & 127) + 1);
                asm volatile("global_store_byte %0, %1, off sc0 sc1"
                             :: "v"(myflag), "v"(fv) : "memory");
            }
        }
        // kh=1 waves run ahead into step t+1 (throttled by the poll there);
        // parity pre[] makes that safe without a trailing barrier.
    }
}

// Output projection: block (tt, nt); wave = batch group g (chain).
__global__ __launch_bounds__(256) void outproj(const ushort* __restrict__ hpan,
                                               const ushort* __restrict__ wof,
                                               const float* __restrict__ bo,
                                               float* __restrict__ out) {
    const int tt   = blockIdx.x;          // 0..255
    const int nt   = blockIdx.y;          // 0..4
    const int tid  = threadIdx.x;
    const int g    = tid >> 6;
    const int lane = tid & 63;
    const ushort* abase = hpan + ((size_t)(tt + 1) * 4 + g) * HSLOT
                          + (lane >> 4) * 128 + (lane & 15) * 8;
    const short8v* wb = (const short8v*)wof;

    floatx4 ac[4] = {{0.f,0.f,0.f,0.f},{0.f,0.f,0.f,0.f},
                     {0.f,0.f,0.f,0.f},{0.f,0.f,0.f,0.f}};
    #pragma unroll 4
    for (int ks = 0; ks < 32; ++ks) {
        short8v av = *(const short8v*)(abase + ks * 512);
        #pragma unroll
        for (int ct = 0; ct < 4; ++ct)
            ac[ct] = __builtin_amdgcn_mfma_f32_16x16x32_bf16(
                av, wb[((nt * 4 + ct) * 32 + ks) * 64 + lane], ac[ct], 0, 0, 0);
    }
    const int orow = tt * 64 + g * 16 + (lane >> 4) * 4;
    #pragma unroll
    for (int ct = 0; ct < 4; ++ct) {
        int n = nt * 64 + ct * 16 + (lane & 15);
        if (n < NCLS) {
            float bias = bo[n];
            #pragma unroll
            for (int j = 0; j < 4; ++j)
                out[(size_t)(orow + j) * NCLS + n] = ac[ct][j] + bias;
        }
    }
}

extern "C" void kernel_launch(void* const* d_in, const int* in_sizes, int n_in,
                              void* d_out, int out_size, void* d_ws, size_t ws_size,
                              hipStream_t stream) {
    const float* x  = (const float*)d_in[0];   // [T,B,FEAT]
    const float* Wx = (const float*)d_in[1];   // [4,4,64,256]
    const float* bx = (const float*)d_in[2];   // [4,HID]
    const float* Wh = (const float*)d_in[3];   // [4,4,256,256]
    const float* Wo = (const float*)d_in[4];   // [HID,NCLS]
    const float* bo = (const float*)d_in[5];   // [NCLS]
    float* out = (float*)d_out;

    // Workspace layout (ushort units), ~53.2 MB total
    ushort* xp   = (ushort*)d_ws;                          // T*4*XSLOT  = 4,194,304
    ushort* wcf  = xp  + (size_t)T * 4 * XSLOT;            // 5,242,880
    ushort* wof  = wcf + (size_t)64 * 4 * 40 * 512;        // 327,680
    ushort* hpan = wof + 327680;                           // (T+1)*4*HSLOT = 16,842,752
    unsigned char* flg = (unsigned char*)(hpan + (size_t)(T + 1) * 4 * HSLOT);

    conv_xpanel<<<(T * B * FEAT / 4) / 256, 256, 0, stream>>>(x, xp);
    prep_wcf<<<(64 * 4 * 40 * 512) / 256, 256, 0, stream>>>(Wh, Wx, wcf);
    prep_wof<<<(20 * 32 * 512) / 256, 256, 0, stream>>>(Wo, wof);
    init_hf<<<64, 256, 0, stream>>>(hpan, flg);

    void* args[] = {(void*)&xp, (void*)&wcf, (void*)&bx, (void*)&hpan, (void*)&flg};
    hipLaunchCooperativeKernel((void*)qlstm_persist, dim3(NBLK), dim3(NTHR),
                               args, 0, stream);

    outproj<<<dim3(T, 5), 256, 0, stream>>>(hpan, wof, bo, out);
}

// Round 14
// 1098.860 us; speedup vs baseline: 2.5861x; 2.5861x over previous
//
#include <hip/hip_runtime.h>
#include <hip/hip_bf16.h>
#include <math.h>

// Problem constants
#define T 256
#define B 64
#define FEAT 256
#define HID 1024
#define NCLS 257
#define KSTEPS 40          // K = 1280 = 40 * 32
#define BH (B * HID)
#define BFEAT (B * FEAT)
#define NBLK 128           // 1 block per 8 hidden columns
#define NTHR 512

typedef __attribute__((ext_vector_type(8))) short short8v;   // 8 x bf16
typedef __attribute__((ext_vector_type(4))) float floatx4;   // MFMA acc

// Hamilton block component/sign tables
__device__ __constant__ int   d_comp[4][4] = {{0,1,2,3},{1,0,3,2},{2,3,0,1},{3,2,1,0}};
__device__ __constant__ float d_sign[4][4] = {{ 1.f, 1.f, 1.f, 1.f},
                                              {-1.f, 1.f,-1.f, 1.f},
                                              {-1.f, 1.f, 1.f,-1.f},
                                              {-1.f,-1.f, 1.f, 1.f}};

__device__ __forceinline__ ushort f2bf(float f) {
    union { float f; unsigned u; } v; v.f = f;
    unsigned r = v.u + 0x7FFF + ((v.u >> 16) & 1);   // RNE
    return (ushort)(r >> 16);
}

__device__ __forceinline__ float sigm(float v) { return 1.f / (1.f + __expf(-v)); }
__device__ __forceinline__ float tanh_fast(float v) { return 1.f - 2.f / (1.f + __expf(2.f * v)); }

// x (fp32 [T][B][FEAT]) -> panel-layout bf16 xpanel[T][FEAT/8][B][8]
__global__ __launch_bounds__(256) void conv_xpanel(const float* __restrict__ x,
                                                   ushort* __restrict__ xp) {
    int i = blockIdx.x * 256 + threadIdx.x;   // over T*B*FEAT/4
    int k4 = i & 63, b = (i >> 6) & 63, t = i >> 12;
    int k = k4 * 4;
    float4 v = ((const float4*)x)[i];
    ushort4 o;
    o.x = f2bf(v.x); o.y = f2bf(v.y); o.z = f2bf(v.z); o.w = f2bf(v.w);
    *(ushort4*)(xp + (size_t)t * BFEAT + (k >> 3) * 512 + b * 8 + (k & 4)) = o;
}

// Build frag-ordered bf16 weights for the SWAPPED orientation (A = W^T):
// e = (((blk*2+mt)*40 + ks)*64 + lane)*8 + j
//   gate col c = mt*16 + (lane&15); hl = c>>2, g = c&3; hidden col n = blk*8+hl
//   k = ks*32 + (lane>>4)*8 + j   (k<1024: Wh rows, else Wx rows)
__global__ __launch_bounds__(256) void prep_wcf(const float* __restrict__ Wh,
                                                const float* __restrict__ Wx,
                                                ushort* __restrict__ wcf) {
    int e = blockIdx.x * 256 + threadIdx.x;   // < 128*2*40*512 = 5,242,880
    int j    = e & 7;
    int lane = (e >> 3) & 63;
    int r    = e >> 9;
    int ks   = r % 40;
    int s    = r / 40;
    int mt   = s & 1;
    int blk  = s >> 1;
    int c  = mt * 16 + (lane & 15);
    int hl = c >> 2, g = c & 3;
    int n  = blk * 8 + hl;
    int qq = n >> 8, bc = n & 255;
    int k  = ks * 32 + ((lane >> 4) << 3) + j;
    float v;
    if (k < HID) {
        int p = k >> 8, a = k & 255;
        v = d_sign[p][qq] * Wh[((g * 4 + d_comp[p][qq]) * 256 + a) * 256 + bc];
    } else {
        int kk = k - HID;
        int p = kk >> 6, a = kk & 63;
        v = d_sign[p][qq] * Wx[((g * 4 + d_comp[p][qq]) * 64 + a) * 256 + bc];
    }
    wcf[e] = f2bf(v);
}

// Wo -> frag-ordered bf16, cols padded to 320 (unchanged orientation: A = h)
__global__ __launch_bounds__(256) void prep_wof(const float* __restrict__ Wo,
                                                ushort* __restrict__ wof) {
    int e = blockIdx.x * 256 + threadIdx.x;   // < 20*32*512 = 327,680
    int j    = e & 7;
    int lane = (e >> 3) & 63;
    int ks   = (e >> 9) & 31;
    int tile = e >> 14;
    int n = tile * 16 + (lane & 15);
    int k = ks * 32 + ((lane >> 4) << 3) + j;
    wof[e] = (n < NCLS) ? f2bf(Wo[k * NCLS + n]) : (ushort)0;
}

// zero h slot 0 and the flag array
__global__ __launch_bounds__(256) void init_hc(ushort* __restrict__ hs0,
                                               uint* __restrict__ flags) {
    int i = blockIdx.x * 256 + threadIdx.x;   // over BH
    hs0[i] = 0;
    if (i < NBLK) flags[i] = 0;
}

#define LOADX4(dst, addr) \
    asm volatile("global_load_dwordx4 %0, %1, off" : "=v"(dst) : "v"(addr))

// Persistent kernel (r7 structure, proven): all 256 LSTM steps. Block blk
// owns hidden cols blk*8..blk*8+7 (32 gate cols = 2 m-tiles). 8 waves:
// khalf = w>>2 splits K, bt = w&3 -> batch rows bt*16..+15.
// h in panel layout [slot][HID/8][B][8]: full-line coalesced stores AND
// coalesced 16B B-frag loads. Gates fully in-thread (1 thread = 1 (b,hidcol)).
// CHANGE vs r7: A-frags loaded via asm-volatile (cannot be rematerialized ->
// 160 VGPRs stay weight-resident) + launch_bounds(512,1) for the 256-VGPR cap
// (grid = 128 blocks on 256 CUs -> 1 block/CU regardless).
__global__ __launch_bounds__(512, 1) void qlstm_persist(
    const ushort* __restrict__ xp,     // [T][FEAT/8][B][8] bf16
    const ushort* __restrict__ wcf,    // frag-ordered weights (A = W^T)
    const float*  __restrict__ bx,     // [4][1024]
    ushort*       __restrict__ hsteps, // [T+1][HID/8][B][8] bf16
    uint*         __restrict__ flags)  // [NBLK] per-block step flags
{
    __shared__ float pre[2][64][36];   // [khalf][batch][gatecol(32), pad 36]

    const int tid   = threadIdx.x;
    const int blk   = blockIdx.x;
    const int w     = tid >> 6;
    const int lane  = tid & 63;
    const int khalf = w >> 2;
    const int bt    = w & 3;
    const int hofs  = khalf * 16;   // h ksteps 0..15 / 16..31
    const int xofs  = khalf * 4;    // x ksteps (local) 0..3 / 4..7

    // ---- one-time: A-fragments (W^T) -> registers via asm loads ----
    const ushort* wb0 = wcf + (size_t)blk * 2 * KSTEPS * 512 + lane * 8;
    short8v Ah[2][16], Ax[2][4];
    #pragma unroll
    for (int mt = 0; mt < 2; ++mt) {
        #pragma unroll
        for (int i = 0; i < 16; ++i)
            LOADX4(Ah[mt][i], wb0 + (mt * KSTEPS + hofs + i) * 512);
        #pragma unroll
        for (int u = 0; u < 4; ++u)
            LOADX4(Ax[mt][u], wb0 + (mt * KSTEPS + 32 + xofs + u) * 512);
    }
    asm volatile("s_waitcnt vmcnt(0)" ::: "memory");
    __builtin_amdgcn_sched_barrier(0);

    // ---- gate identity: thread -> (gb = batch, hc = hidden-local) ----
    const int gb = tid >> 3;
    const int hc = tid & 7;
    const int gn = blk * 8 + hc;
    const float bxf = bx[gn], bxi = bx[HID + gn];
    const float bxo = bx[2 * HID + gn], bxa = bx[3 * HID + gn];
    float c_reg = 0.f;

    // B-frag lane offset (shorts): (panel-row lane>>4)*512 + batch*8
    const int boff = (lane >> 4) * 512 + (bt * 16 + (lane & 15)) * 8;

    for (int t = 0; t < T; ++t) {
        floatx4 acc0 = {0.f,0.f,0.f,0.f}, acc1 = {0.f,0.f,0.f,0.f};

        // x-part (independent of h_t) — before the barrier
        const ushort* xrow = xp + (size_t)t * BFEAT + boff;
        #pragma unroll
        for (int u = 0; u < 4; ++u) {
            short8v bv = *(const short8v*)(xrow + (xofs + u) * 2048);
            acc0 = __builtin_amdgcn_mfma_f32_16x16x32_bf16(Ax[0][u], bv, acc0, 0, 0, 0);
            acc1 = __builtin_amdgcn_mfma_f32_16x16x32_bf16(Ax[1][u], bv, acc1, 0, 0, 0);
        }

        // barrier: every wave polls all 128 flags (2 per lane)
        if (t > 0) {
            const uint tgt = (uint)t;
            for (;;) {
                uint f0 = __hip_atomic_load(flags + lane,      __ATOMIC_RELAXED, __HIP_MEMORY_SCOPE_AGENT);
                uint f1 = __hip_atomic_load(flags + 64 + lane, __ATOMIC_RELAXED, __HIP_MEMORY_SCOPE_AGENT);
                if (__all((f0 >= tgt) && (f1 >= tgt))) break;
                __builtin_amdgcn_s_sleep(1);
            }
        }

        // h-part: 16 coalesced 16B B-frag loads from panel layout
        const ushort* hrow = hsteps + (size_t)t * BH + boff;
        #pragma unroll
        for (int i = 0; i < 16; ++i) {
            short8v bv = *(const short8v*)(hrow + (hofs + i) * 2048);
            acc0 = __builtin_amdgcn_mfma_f32_16x16x32_bf16(Ah[0][i], bv, acc0, 0, 0, 0);
            acc1 = __builtin_amdgcn_mfma_f32_16x16x32_bf16(Ah[1][i], bv, acc1, 0, 0, 0);
        }

        // D layout: n(batch) = lane&15, m(gatecol-in-tile) = (lane>>4)*4 + jj
        {
            const int pb = bt * 16 + (lane & 15);
            const int pm = (lane >> 4) * 4;
            #pragma unroll
            for (int jj = 0; jj < 4; ++jj) {
                pre[khalf][pb][pm + jj]      = acc0[jj];
                pre[khalf][pb][16 + pm + jj] = acc1[jj];
            }
        }
        __syncthreads();

        // gates: in-thread, c in register
        {
            float4 p0 = *(const float4*)&pre[0][gb][hc * 4];
            float4 p1 = *(const float4*)&pre[1][gb][hc * 4];
            float f  = sigm(p0.x + p1.x + bxf);
            float i_ = sigm(p0.y + p1.y + bxi);
            float o  = sigm(p0.z + p1.z + bxo);
            float a  = p0.w + p1.w + bxa;
            c_reg = i_ * tanh_fast(a) + f * c_reg;
            float h = o * tanh_fast(c_reg);
            uint hvu = f2bf(h);
            ushort* hp = hsteps + (size_t)(t + 1) * BH + blk * 512 + tid;
            asm volatile("global_store_short %0, %1, off sc0 sc1"
                         :: "v"(hp), "v"(hvu) : "memory");
            asm volatile("s_waitcnt vmcnt(0)" ::: "memory");
        }
        __syncthreads();   // all full-line h stores of this block drained

        if (t < T - 1 && tid == 0)
            __hip_atomic_store(flags + blk, (uint)(t + 1),
                               __ATOMIC_RELAXED, __HIP_MEMORY_SCOPE_AGENT);
    }
}

// Output projection via MFMA: block (t, nt): rows t*64..t*64+63 (one t),
// cols nt*64..+63 masked to 257. A-frags read h from panel layout.
__global__ __launch_bounds__(256) void outproj(const ushort* __restrict__ hsteps,
                                               const ushort* __restrict__ wof,
                                               const float* __restrict__ bo,
                                               float* __restrict__ out) {
    const int tt   = blockIdx.x;          // 0..255 (= t)
    const int nt   = blockIdx.y;          // 0..4
    const int tid  = threadIdx.x;
    const int w    = tid >> 6;
    const int lane = tid & 63;
    const int b    = w * 16 + (lane & 15);
    const ushort* abase = hsteps + (size_t)(tt + 1) * BH + (lane >> 4) * 512 + b * 8;
    const short8v* wb  = (const short8v*)wof;

    floatx4 ac[4] = {{0.f,0.f,0.f,0.f},{0.f,0.f,0.f,0.f},
                     {0.f,0.f,0.f,0.f},{0.f,0.f,0.f,0.f}};
    #pragma unroll 4
    for (int ks = 0; ks < 32; ++ks) {
        short8v av = *(const short8v*)(abase + ks * 2048);
        #pragma unroll
        for (int ct = 0; ct < 4; ++ct)
            ac[ct] = __builtin_amdgcn_mfma_f32_16x16x32_bf16(
                av, wb[((nt * 4 + ct) * 32 + ks) * 64 + lane], ac[ct], 0, 0, 0);
    }
    const int orow = tt * 64 + w * 16 + (lane >> 4) * 4;
    #pragma unroll
    for (int ct = 0; ct < 4; ++ct) {
        int n = nt * 64 + ct * 16 + (lane & 15);
        if (n < NCLS) {
            float bias = bo[n];
            #pragma unroll
            for (int j = 0; j < 4; ++j)
                out[(size_t)(orow + j) * NCLS + n] = ac[ct][j] + bias;
        }
    }
}

extern "C" void kernel_launch(void* const* d_in, const int* in_sizes, int n_in,
                              void* d_out, int out_size, void* d_ws, size_t ws_size,
                              hipStream_t stream) {
    const float* x  = (const float*)d_in[0];   // [T,B,FEAT]
    const float* Wx = (const float*)d_in[1];   // [4,4,64,256]
    const float* bx = (const float*)d_in[2];   // [4,HID]
    const float* Wh = (const float*)d_in[3];   // [4,4,256,256]
    const float* Wo = (const float*)d_in[4];   // [HID,NCLS]
    const float* bo = (const float*)d_in[5];   // [NCLS]
    float* out = (float*)d_out;

    // Workspace layout (ushort units), ~53.2 MB total
    ushort* xp     = (ushort*)d_ws;                        // 4,194,304
    ushort* wcf    = xp  + (size_t)T * BFEAT;              // 5,242,880
    ushort* wof    = wcf + (size_t)NBLK * 2 * KSTEPS * 512;// 327,680
    ushort* hsteps = wof + 327680;                         // (T+1)*BH = 16,842,752
    uint*   flags  = (uint*)(hsteps + (size_t)(T + 1) * BH);

    conv_xpanel<<<(T * B * FEAT / 4) / 256, 256, 0, stream>>>(x, xp);
    prep_wcf<<<(NBLK * 2 * KSTEPS * 512) / 256, 256, 0, stream>>>(Wh, Wx, wcf);
    prep_wof<<<(20 * 32 * 512) / 256, 256, 0, stream>>>(Wo, wof);
    init_hc<<<BH / 256, 256, 0, stream>>>(hsteps, flags);

    void* args[] = {(void*)&xp, (void*)&wcf, (void*)&bx, (void*)&hsteps, (void*)&flags};
    hipLaunchCooperativeKernel((void*)qlstm_persist, dim3(NBLK), dim3(NTHR),
                               args, 0, stream);

    outproj<<<dim3(T, 5), 256, 0, stream>>>(hsteps, wof, bo, out);
}